// Round 5
// baseline (1311.511 us; speedup 1.0000x reference)
//
#include <hip/hip_runtime.h>

#define NN 50000
#define LL 4
#define DD 128
#define KDIM 16
#define EE 800000
#define MM (NN * LL)
#define DECAYF 0.7f
#define EPSF 1e-5f
#define SCAN_CHUNK 512
#define SCAN_NBLK ((NN + SCAN_CHUNK - 1) / SCAN_CHUNK)   // 98

// ---------- CSR build ----------
__global__ void k_zero(int* p, int n) {
    int i = blockIdx.x * 256 + threadIdx.x;
    if (i < n) p[i] = 0;
}
__global__ void k_hist(const int* __restrict__ rows, int* __restrict__ counts) {
    int e = blockIdx.x * 256 + threadIdx.x;
    if (e < EE) atomicAdd(&counts[rows[e]], 1);
}
__global__ void k_scan1(const int* __restrict__ counts, int* __restrict__ offs, int* __restrict__ csum) {
    __shared__ int s[SCAN_CHUNK];
    int i = blockIdx.x * SCAN_CHUNK + threadIdx.x;
    int v = (i < NN) ? counts[i] : 0;
    s[threadIdx.x] = v;
    __syncthreads();
    for (int off = 1; off < SCAN_CHUNK; off <<= 1) {
        int t = (threadIdx.x >= off) ? s[threadIdx.x - off] : 0;
        __syncthreads();
        s[threadIdx.x] += t;
        __syncthreads();
    }
    if (i < NN) offs[i] = s[threadIdx.x] - v;
    if (threadIdx.x == SCAN_CHUNK - 1) csum[blockIdx.x] = s[SCAN_CHUNK - 1];
}
__global__ void k_scan2(int* __restrict__ csum) {
    __shared__ int s[128];
    int v = (threadIdx.x < SCAN_NBLK) ? csum[threadIdx.x] : 0;
    s[threadIdx.x] = v;
    __syncthreads();
    for (int off = 1; off < 128; off <<= 1) {
        int t = (threadIdx.x >= off) ? s[threadIdx.x - off] : 0;
        __syncthreads();
        s[threadIdx.x] += t;
        __syncthreads();
    }
    if (threadIdx.x < SCAN_NBLK) csum[threadIdx.x] = s[threadIdx.x] - v;
}
__global__ void k_scan3(int* __restrict__ offs, const int* __restrict__ csum, int* __restrict__ cursor) {
    int i = blockIdx.x * SCAN_CHUNK + threadIdx.x;
    if (i < NN) {
        int v = offs[i] + csum[blockIdx.x];
        offs[i] = v;
        cursor[i] = v;
    } else if (i == NN) {
        offs[NN] = EE;
    }
}
__global__ void k_fill(const int* __restrict__ rows, const int* __restrict__ cols,
                       const float* __restrict__ vals,
                       int* __restrict__ cursor, int* __restrict__ ccol, float* __restrict__ cval) {
    int e = blockIdx.x * 256 + threadIdx.x;
    if (e < EE) {
        int r = rows[e];
        int pos = atomicAdd(&cursor[r], 1);
        ccol[pos] = cols[e];
        cval[pos] = vals[e];
    }
}

// ---------- SAGE aggregation -> io (f32): agg[l,n,d] = sum_e(row=n) val * x[l,col,d] ----------
__global__ __launch_bounds__(128) void k_agg(const int* __restrict__ offs, const int* __restrict__ ccol,
                                             const float* __restrict__ cval,
                                             const float* __restrict__ x,
                                             float* __restrict__ agg) {
    int n = blockIdx.x;
    int tid = threadIdx.x;    // = d
    int s = offs[n], e = offs[n + 1];
    float a0 = 0.f, a1 = 0.f, a2 = 0.f, a3 = 0.f;
    for (int p = s; p < e; p++) {
        int c = ccol[p];
        float w = cval[p];
        a0 += w * x[((size_t)(0 * NN + c)) * DD + tid];
        a1 += w * x[((size_t)(1 * NN + c)) * DD + tid];
        a2 += w * x[((size_t)(2 * NN + c)) * DD + tid];
        a3 += w * x[((size_t)(3 * NN + c)) * DD + tid];
    }
    agg[((size_t)(0 * NN + n)) * DD + tid] = a0;
    agg[((size_t)(1 * NN + n)) * DD + tid] = a1;
    agg[((size_t)(2 * NN + n)) * DD + tid] = a2;
    agg[((size_t)(3 * NN + n)) * DD + tid] = a3;
}

// ---------- f32 tile loaders ----------
__device__ __forceinline__ void load_w_tile(const float* __restrict__ W, int kbase, float* wt) {
    for (int t = threadIdx.x; t < 512; t += 256) {
        int kk = t >> 4;
        int c = (t & 15) * 8;
        float4 a = *reinterpret_cast<const float4*>(&W[(size_t)(kbase + kk) * DD + c]);
        float4 b = *reinterpret_cast<const float4*>(&W[(size_t)(kbase + kk) * DD + c + 4]);
        float* d = &wt[kk * DD + c];
        d[0] = a.x; d[1] = a.y; d[2] = a.z; d[3] = a.w;
        d[4] = b.x; d[5] = b.y; d[6] = b.z; d[7] = b.w;
    }
}
__device__ __forceinline__ void load_in_tile(const float* __restrict__ in, int rowbase, int kbase, float* it) {
    int t = threadIdx.x;
    int row = t >> 2;
    int ko = (t & 3) * 8;
    float4 a = *reinterpret_cast<const float4*>(&in[(size_t)(rowbase + row) * DD + kbase + ko]);
    float4 b = *reinterpret_cast<const float4*>(&in[(size_t)(rowbase + row) * DD + kbase + ko + 4]);
    float* d = &it[row * 33 + ko];
    d[0] = a.x; d[1] = a.y; d[2] = a.z; d[3] = a.w;
    d[4] = b.x; d[5] = b.y; d[6] = b.z; d[7] = b.w;
}
__device__ __forceinline__ void fma_tile(const float* __restrict__ wt, const float* __restrict__ it,
                                         int ty, int tx, float acc[4][8]) {
    #pragma unroll 8
    for (int kk = 0; kk < 32; kk++) {
        float4 w0 = *reinterpret_cast<const float4*>(&wt[kk * DD + tx * 8]);
        float4 w1 = *reinterpret_cast<const float4*>(&wt[kk * DD + tx * 8 + 4]);
        #pragma unroll
        for (int i = 0; i < 4; i++) {
            float a = it[(ty * 4 + i) * 33 + kk];
            acc[i][0] += a * w0.x; acc[i][1] += a * w0.y; acc[i][2] += a * w0.z; acc[i][3] += a * w0.w;
            acc[i][4] += a * w1.x; acc[i][5] += a * w1.y; acc[i][6] += a * w1.z; acc[i][7] += a * w1.w;
        }
    }
}

// ---------- fused (1|2)x GEMM [64x128,K=128] + bias/res/scale/silu + LayerNorm, f32 ----------
// In-place (out_ aliasing in1_/in2_) is safe: all global reads of this block's 64 rows
// complete behind __syncthreads() before the epilogue writes them.
template <int NIN, bool BIAS, bool RES, bool SCALE, bool SILU>
__global__ __launch_bounds__(256) void k_fused(
    const float* __restrict__ in1_, const float* __restrict__ W1,
    const float* __restrict__ in2_, const float* __restrict__ W2,
    const float* __restrict__ res_, const float* __restrict__ bias,
    const float* __restrict__ wtbuf,
    const float* __restrict__ g, const float* __restrict__ bb,
    float* __restrict__ out_) {
    __shared__ float smem[64 * 129];   // 33 KB
    float* wt = smem;
    float* it = smem + 4096;
    int rowbase = blockIdx.x * 64;
    int ty = threadIdx.x >> 4, tx = threadIdx.x & 15;

    float acc[4][8];
    #pragma unroll
    for (int i = 0; i < 4; i++)
        #pragma unroll
        for (int j = 0; j < 8; j++) acc[i][j] = 0.f;

    #pragma unroll 1
    for (int ph = 0; ph < 4; ph++) {
        load_w_tile(W1, ph * 32, wt);
        load_in_tile(in1_, rowbase, ph * 32, it);
        __syncthreads();
        fma_tile(wt, it, ty, tx, acc);
        __syncthreads();
    }
    if (NIN == 2) {
        #pragma unroll 1
        for (int ph = 0; ph < 4; ph++) {
            load_w_tile(W2, ph * 32, wt);
            load_in_tile(in2_, rowbase, ph * 32, it);
            __syncthreads();
            fma_tile(wt, it, ty, tx, acc);
            __syncthreads();
        }
    }

    float bias_r[8];
    if (BIAS) {
        #pragma unroll
        for (int j = 0; j < 8; j++) bias_r[j] = bias[tx * 8 + j];
    }
    #pragma unroll
    for (int i = 0; i < 4; i++) {
        int row = ty * 4 + i;
        size_t m = (size_t)rowbase + row;
        float wscale = 1.f;
        if (SCALE) {
            int l = (int)(m / NN), n = (int)(m % NN);
            wscale = wtbuf[n * LL + l];
        }
        #pragma unroll
        for (int j = 0; j < 8; j++) {
            float y = acc[i][j];
            if (BIAS) y += bias_r[j];
            if (RES) y += res_[m * DD + tx * 8 + j];
            if (SCALE) y *= wscale;
            if (SILU) y = y / (1.f + expf(-y));
            smem[row * 129 + tx * 8 + j] = y;
        }
    }
    __syncthreads();

    int wv = threadIdx.x >> 6, lane = threadIdx.x & 63;
    float g0 = g[lane], g1 = g[64 + lane];
    float bb0 = bb[lane], bb1 = bb[64 + lane];
    #pragma unroll 1
    for (int rr = 0; rr < 16; rr++) {
        int row = wv * 16 + rr;
        size_t m = (size_t)rowbase + row;
        float y0 = smem[row * 129 + lane], y1 = smem[row * 129 + 64 + lane];
        float s = y0 + y1, q = y0 * y0 + y1 * y1;
        #pragma unroll
        for (int off = 32; off; off >>= 1) {
            s += __shfl_xor(s, off, 64);
            q += __shfl_xor(q, off, 64);
        }
        float mean = s * (1.f / 128.f);
        float var = fmaxf(q * (1.f / 128.f) - mean * mean, 0.f);
        float rstd = rsqrtf(var + EPSF);
        out_[m * DD + lane]      = (y0 - mean) * rstd * g0 + bb0;
        out_[m * DD + 64 + lane] = (y1 - mean) * rstd * g1 + bb1;
    }
}

// ---------- lin1 with inline att branch ----------
// atile = LN((x@Wv) * w) in LDS, then h1 = LN(silu(sage@W1a + atile@W1b + b)) -> sage_io.
__global__ __launch_bounds__(256) void k_lin1(
    const float* __restrict__ x, const float* __restrict__ Wv,
    const float* __restrict__ wtbuf,
    const float* __restrict__ att_g, const float* __restrict__ att_b,
    float* __restrict__ sage_io,
    const float* __restrict__ W1a,
    const float* __restrict__ bias,
    const float* __restrict__ g, const float* __restrict__ bb) {
    const float* W1b = W1a + (size_t)DD * DD;
    __shared__ float smem[6208];        // wt[4096] + it[2112]
    __shared__ float atile[64 * 128];   // 32 KB
    float* wt = smem;
    float* it = smem + 4096;
    int rowbase = blockIdx.x * 64;
    int ty = threadIdx.x >> 4, tx = threadIdx.x & 15;
    int wv = threadIdx.x >> 6, lane = threadIdx.x & 63;

    float acc[4][8];
    #pragma unroll
    for (int i = 0; i < 4; i++)
        #pragma unroll
        for (int j = 0; j < 8; j++) acc[i][j] = 0.f;

    // x @ Wv
    #pragma unroll 1
    for (int ph = 0; ph < 4; ph++) {
        load_w_tile(Wv, ph * 32, wt);
        load_in_tile(x, rowbase, ph * 32, it);
        __syncthreads();
        fma_tile(wt, it, ty, tx, acc);
        __syncthreads();
    }
    #pragma unroll
    for (int i = 0; i < 4; i++) {
        int row = ty * 4 + i;
        size_t m = (size_t)rowbase + row;
        int l = (int)(m / NN), n = (int)(m % NN);
        float w = wtbuf[n * LL + l];
        #pragma unroll
        for (int j = 0; j < 8; j++) atile[row * 128 + tx * 8 + j] = acc[i][j] * w;
    }
    __syncthreads();
    {
        float g0 = att_g[lane], g1 = att_g[64 + lane];
        float b0 = att_b[lane], b1 = att_b[64 + lane];
        #pragma unroll 1
        for (int rr = 0; rr < 16; rr++) {
            int row = wv * 16 + rr;
            float y0 = atile[row * 128 + lane], y1 = atile[row * 128 + 64 + lane];
            float s = y0 + y1, q = y0 * y0 + y1 * y1;
            #pragma unroll
            for (int off = 32; off; off >>= 1) {
                s += __shfl_xor(s, off, 64);
                q += __shfl_xor(q, off, 64);
            }
            float mean = s * (1.f / 128.f);
            float var = fmaxf(q * (1.f / 128.f) - mean * mean, 0.f);
            float rstd = rsqrtf(var + EPSF);
            atile[row * 128 + lane]      = (y0 - mean) * rstd * g0 + b0;
            atile[row * 128 + 64 + lane] = (y1 - mean) * rstd * g1 + b1;
        }
    }
    __syncthreads();

    // h1 = sage @ W1a + atile @ W1b
    #pragma unroll
    for (int i = 0; i < 4; i++)
        #pragma unroll
        for (int j = 0; j < 8; j++) acc[i][j] = 0.f;

    #pragma unroll 1
    for (int ph = 0; ph < 4; ph++) {
        load_w_tile(W1a, ph * 32, wt);
        load_in_tile(sage_io, rowbase, ph * 32, it);
        __syncthreads();
        fma_tile(wt, it, ty, tx, acc);
        __syncthreads();
    }
    #pragma unroll 1
    for (int ph = 0; ph < 4; ph++) {
        load_w_tile(W1b, ph * 32, wt);
        __syncthreads();
        #pragma unroll 8
        for (int kk = 0; kk < 32; kk++) {
            float4 w0 = *reinterpret_cast<const float4*>(&wt[kk * DD + tx * 8]);
            float4 w1 = *reinterpret_cast<const float4*>(&wt[kk * DD + tx * 8 + 4]);
            #pragma unroll
            for (int i = 0; i < 4; i++) {
                float a = atile[(ty * 4 + i) * 128 + ph * 32 + kk];
                acc[i][0] += a * w0.x; acc[i][1] += a * w0.y; acc[i][2] += a * w0.z; acc[i][3] += a * w0.w;
                acc[i][4] += a * w1.x; acc[i][5] += a * w1.y; acc[i][6] += a * w1.z; acc[i][7] += a * w1.w;
            }
        }
        __syncthreads();
    }

    float bias_r[8];
    #pragma unroll
    for (int j = 0; j < 8; j++) bias_r[j] = bias[tx * 8 + j];
    #pragma unroll
    for (int i = 0; i < 4; i++) {
        int row = ty * 4 + i;
        #pragma unroll
        for (int j = 0; j < 8; j++) {
            float y = acc[i][j] + bias_r[j];
            y = y / (1.f + expf(-y));
            atile[row * 128 + tx * 8 + j] = y;
        }
    }
    __syncthreads();
    {
        float g0 = g[lane], g1 = g[64 + lane];
        float b0 = bb[lane], b1 = bb[64 + lane];
        #pragma unroll 1
        for (int rr = 0; rr < 16; rr++) {
            int row = wv * 16 + rr;
            size_t m = (size_t)rowbase + row;
            float y0 = atile[row * 128 + lane], y1 = atile[row * 128 + 64 + lane];
            float s = y0 + y1, q = y0 * y0 + y1 * y1;
            #pragma unroll
            for (int off = 32; off; off >>= 1) {
                s += __shfl_xor(s, off, 64);
                q += __shfl_xor(q, off, 64);
            }
            float mean = s * (1.f / 128.f);
            float var = fmaxf(q * (1.f / 128.f) - mean * mean, 0.f);
            float rstd = rsqrtf(var + EPSF);
            sage_io[m * DD + lane]      = (y0 - mean) * rstd * g0 + b0;
            sage_io[m * DD + 64 + lane] = (y1 - mean) * rstd * g1 + b1;
        }
    }
}

// ---------- k,q projection + weights0 = mean(k*q) ----------
__global__ __launch_bounds__(256) void k_kq(const float* __restrict__ x,
                                            const float* __restrict__ Wk,
                                            const float* __restrict__ Wq,
                                            float* __restrict__ wt_total, float* __restrict__ iw0) {
    __shared__ float xt[64 * 129];
    __shared__ float kw[128 * 32];   // cols 0..15 = Wk, 16..31 = Wq
    int rowbase = blockIdx.x * 64;
    for (int t = threadIdx.x; t < 1024; t += 256) {
        int row = t >> 4;
        int co = (t & 15) * 8;
        float4 a = *reinterpret_cast<const float4*>(&x[(size_t)(rowbase + row) * DD + co]);
        float4 b = *reinterpret_cast<const float4*>(&x[(size_t)(rowbase + row) * DD + co + 4]);
        float* d = &xt[row * 129 + co];
        d[0] = a.x; d[1] = a.y; d[2] = a.z; d[3] = a.w;
        d[4] = b.x; d[5] = b.y; d[6] = b.z; d[7] = b.w;
    }
    {
        int t = threadIdx.x;
        int k = t >> 1, jh = (t & 1) * 8;
        #pragma unroll
        for (int j = 0; j < 8; j++) {
            kw[k * 32 + jh + j]      = Wk[(size_t)k * KDIM + jh + j];
            kw[k * 32 + 16 + jh + j] = Wq[(size_t)k * KDIM + jh + j];
        }
    }
    __syncthreads();
    int r = threadIdx.x & 63, grp = threadIdx.x >> 6;
    float acc[8];
    #pragma unroll
    for (int j = 0; j < 8; j++) acc[j] = 0.f;
    for (int k = 0; k < 128; k++) {
        float a = xt[r * 129 + k];
        float4 w0 = *reinterpret_cast<const float4*>(&kw[k * 32 + grp * 8]);
        float4 w1 = *reinterpret_cast<const float4*>(&kw[k * 32 + grp * 8 + 4]);
        acc[0] += a * w0.x; acc[1] += a * w0.y; acc[2] += a * w0.z; acc[3] += a * w0.w;
        acc[4] += a * w1.x; acc[5] += a * w1.y; acc[6] += a * w1.z; acc[7] += a * w1.w;
    }
    __syncthreads();
    float* yt = xt;   // reuse as [64][33]
    #pragma unroll
    for (int j = 0; j < 8; j++) yt[r * 33 + grp * 8 + j] = acc[j];
    __syncthreads();
    if (threadIdx.x < 64) {
        int row = threadIdx.x;
        float s = 0.f;
        #pragma unroll
        for (int j = 0; j < 16; j++) s += yt[row * 33 + j] * yt[row * 33 + 16 + j];
        s *= (1.f / 16.f);
        size_t m = (size_t)rowbase + row;
        int l = (int)(m / NN), n = (int)(m % NN);
        wt_total[n * LL + l] = s;
        iw0[n * LL + l] = s;
    }
}

// ---------- retentive weight iteration: out = DECAY * spmm(in); wtot += out ----------
__global__ __launch_bounds__(256) void k_spmm_w(const int* __restrict__ offs, const int* __restrict__ ccol,
                                                const float* __restrict__ cval,
                                                const float* __restrict__ win, float* __restrict__ wout,
                                                float* __restrict__ wtot) {
    int i = blockIdx.x * 256 + threadIdx.x;
    if (i >= NN * LL) return;
    int n = i >> 2, l = i & 3;
    int s = offs[n], e = offs[n + 1];
    float a = 0.f;
    for (int p = s; p < e; p++) a += cval[p] * win[(ccol[p] << 2) | l];
    a *= DECAYF;
    wout[i] = a;
    wtot[i] += a;
}

extern "C" void kernel_launch(void* const* d_in, const int* in_sizes, int n_in,
                              void* d_out, int out_size, void* d_ws, size_t ws_size,
                              hipStream_t stream) {
    const float* x        = (const float*)d_in[0];
    const int*   ei       = (const int*)d_in[1];
    const float* evals    = (const float*)d_in[2];
    const float* sage_W   = (const float*)d_in[3];
    const float* sage_b   = (const float*)d_in[4];
    const float* sage_aggW= (const float*)d_in[5];
    const float* sage_ln_g= (const float*)d_in[6];
    const float* sage_ln_b= (const float*)d_in[7];
    const float* att_Wk   = (const float*)d_in[8];
    const float* att_Wq   = (const float*)d_in[9];
    const float* att_Wv   = (const float*)d_in[10];
    const float* att_ln_g = (const float*)d_in[11];
    const float* att_ln_b = (const float*)d_in[12];
    const float* lin1_W   = (const float*)d_in[13];
    const float* lin1_b   = (const float*)d_in[14];
    const float* lin2_W   = (const float*)d_in[15];
    const float* lin2_b   = (const float*)d_in[16];
    const float* ln1_g    = (const float*)d_in[17];
    const float* ln1_b    = (const float*)d_in[18];
    const float* ln2_g    = (const float*)d_in[19];
    const float* ln2_b    = (const float*)d_in[20];

    const int* rows = ei;
    const int* cols = ei + EE;

    // ---- workspace: ~9.4 MB ----
    float* wt_total = (float*)d_ws;                       // [N*L]
    float* iw0      = wt_total + MM;
    float* iw1      = iw0 + MM;
    float* cval     = iw1 + MM;                           // [E]
    int*   counts   = (int*)(cval + EE);                  // N
    int*   offs     = counts + NN;                        // N+1
    int*   cursor   = offs + NN + 1;                      // N
    int*   csum     = cursor + NN;                        // 128
    int*   ccol     = csum + 128;                         // E
    float* io       = (float*)d_out;                      // [M,D] f32: agg -> sage -> h1 -> out

    // ---- CSR build ----
    k_zero<<<(NN + 255) / 256, 256, 0, stream>>>(counts, NN);
    k_hist<<<(EE + 255) / 256, 256, 0, stream>>>(rows, counts);
    k_scan1<<<SCAN_NBLK, SCAN_CHUNK, 0, stream>>>(counts, offs, csum);
    k_scan2<<<1, 128, 0, stream>>>(csum);
    k_scan3<<<SCAN_NBLK, SCAN_CHUNK, 0, stream>>>(offs, csum, cursor);
    k_fill<<<(EE + 255) / 256, 256, 0, stream>>>(rows, cols, evals, cursor, ccol, cval);

    // ---- retentive weights ----
    k_kq<<<MM / 64, 256, 0, stream>>>(x, att_Wk, att_Wq, wt_total, iw0);
    k_spmm_w<<<(MM + 255) / 256, 256, 0, stream>>>(offs, ccol, cval, iw0, iw1, wt_total);
    k_spmm_w<<<(MM + 255) / 256, 256, 0, stream>>>(offs, ccol, cval, iw1, iw0, wt_total);

    // ---- SAGE aggregation -> io ----
    k_agg<<<NN, 128, 0, stream>>>(offs, ccol, cval, x, io);

    // ---- sage_out = LN(silu(x@W + b + agg@aggW)) -> io in-place ----
    k_fused<2, true, false, false, true><<<MM / 64, 256, 0, stream>>>(
        x, sage_W, io, sage_aggW, nullptr, sage_b, nullptr, sage_ln_g, sage_ln_b, io);

    // ---- h1 = LN(silu(sage@W1a + LN((x@Wv)*w)@W1b + b)) -> io in-place ----
    k_lin1<<<MM / 64, 256, 0, stream>>>(
        x, att_Wv, wt_total, att_ln_g, att_ln_b, io,
        lin1_W, lin1_b, ln1_g, ln1_b);

    // ---- out = LN(silu(h1@lin2 + b + x)) -> io (= d_out) in-place ----
    k_fused<1, true, true, false, true><<<MM / 64, 256, 0, stream>>>(
        io, lin2_W, nullptr, nullptr, x, lin2_b, nullptr, ln2_g, ln2_b, io);

    (void)in_sizes; (void)n_in; (void)out_size; (void)ws_size;
}